// Round 6
// baseline (80.404 us; speedup 1.0000x reference)
//
#include <hip/hip_runtime.h>
#include <math.h>

// QuixerCore on gfx950 — register-resident statevector, v6 (code-size focused).
//  * ONE APPLY_CORE code instance in a #pragma unroll 1 two-pass loop
//    (pass 0: token unitary k=2 + LCU exchange + normalize; pass 1: U_ff).
//  * Phase A: fused per-q float4 loads + FMA (2-deep pipeline, low VGPR).
//  * k=1 closed form (U_t|0> real, tensor product of (c,s)).
//  * Butterflies: packed-f32 reg stages + XOR-swizzled LDS transpose + DPP
//    quad_perm for qubit 5. Reductions: DPP row_shr/row_bcast + readlane.
//
// Layout A: lane L holds sv[r] = state[(r<<6)|L] (qubit q<5 -> r bit 4-q,
//           qubit 5..10 -> lane bit 10-q).
// Layout B: lane L holds sv[r] = state[(L<<5)|r] (qubit 6..10 -> r bit 10-q,
//           qubit 5 -> lane bit 0, qubit 0..4 -> lane bits 5..1).

#define NQ 11
typedef float v2f __attribute__((ext_vector_type(2)));

__device__ __forceinline__ v2f splat(float x) { v2f v; v.x = x; v.y = x; return v; }

template<int CTRL>
__device__ __forceinline__ float dpp_mov(float x) {
    return __int_as_float(__builtin_amdgcn_update_dpp(
        0, __float_as_int(x), CTRL, 0xF, 0xF, false));
}

// full-wave sum, uniform result
__device__ __forceinline__ float wave_sum(float v) {
    v += dpp_mov<0x111>(v);   // row_shr:1
    v += dpp_mov<0x112>(v);   // row_shr:2
    v += dpp_mov<0x114>(v);   // row_shr:4
    v += dpp_mov<0x118>(v);   // row_shr:8
    v += dpp_mov<0x142>(v);   // row_bcast:15
    v += dpp_mov<0x143>(v);   // row_bcast:31
    return __int_as_float(__builtin_amdgcn_readlane(__float_as_int(v), 63));
}

// RY butterfly on register-bit mask m with coefficient arrays CC/SS
#define REG_STAGE(CC, SS, q, m) do {                                          \
    const v2f cq_ = splat(CC[q]), sq_ = splat(SS[q]);                         \
    _Pragma("unroll")                                                         \
    for (int r_ = 0; r_ < 32; r_++) {                                         \
        if (!(r_ & (m))) {                                                    \
            const int b_ = r_ | (m);                                          \
            const v2f a_ = sv[r_], b2_ = sv[b_];                              \
            sv[r_] = cq_ * a_ - sq_ * b2_;                                    \
            sv[b_] = sq_ * a_ + cq_ * b2_;                                    \
        }                                                                     \
    }                                                                         \
} while (0)

// RY butterfly on lane bit 0 (qubit 5, layout B) via DPP quad_perm [1,0,3,2]
#define DPP_STAGE(CC, SS) do {                                                \
    const v2f cq_ = splat(CC[5]);                                             \
    const v2f ssn_ = splat((lane & 1) ? SS[5] : -SS[5]);                      \
    _Pragma("unroll")                                                         \
    for (int r_ = 0; r_ < 32; r_++) {                                         \
        v2f p_;                                                               \
        p_.x = dpp_mov<0xB1>(sv[r_].x);                                       \
        p_.y = dpp_mov<0xB1>(sv[r_].y);                                       \
        sv[r_] = cq_ * sv[r_] + ssn_ * p_;                                    \
    }                                                                         \
} while (0)

// transposes, XOR swizzle physical = i ^ ((i>>6)&15): conflict-free both ways.
#define T_A2B() do {                                                          \
    _Pragma("unroll")                                                         \
    for (int r_ = 0; r_ < 32; r_++) {                                         \
        const int i_ = (r_ << 6) | lane;                                      \
        ws[i_ ^ (r_ & 15)] = make_float2(sv[r_].x, sv[r_].y);                 \
    }                                                                         \
    _Pragma("unroll")                                                         \
    for (int r_ = 0; r_ < 32; r_++) {                                         \
        const float2 v_ = ws[((lane << 5) | r_) ^ ((lane >> 1) & 15)];        \
        sv[r_].x = v_.x; sv[r_].y = v_.y;                                     \
    }                                                                         \
} while (0)

#define T_B2A() do {                                                          \
    _Pragma("unroll")                                                         \
    for (int r_ = 0; r_ < 32; r_++) {                                         \
        ws[((lane << 5) | r_) ^ ((lane >> 1) & 15)] =                         \
            make_float2(sv[r_].x, sv[r_].y);                                  \
    }                                                                         \
    _Pragma("unroll")                                                         \
    for (int r_ = 0; r_ < 32; r_++) {                                         \
        const float2 v_ = ws[((r_ << 6) | lane) ^ (r_ & 15)];                 \
        sv[r_].x = v_.x; sv[r_].y = v_.y;                                     \
    }                                                                         \
} while (0)

// full U (11 RYs): layout A in -> layout B out
#define APPLY_CORE(CC, SS) do {                                               \
    REG_STAGE(CC, SS, 0, 16); REG_STAGE(CC, SS, 1, 8);                        \
    REG_STAGE(CC, SS, 2, 4);  REG_STAGE(CC, SS, 3, 2);                        \
    REG_STAGE(CC, SS, 4, 1);                                                  \
    T_A2B();                                                                  \
    REG_STAGE(CC, SS, 6, 16); REG_STAGE(CC, SS, 7, 8);                        \
    REG_STAGE(CC, SS, 8, 4);  REG_STAGE(CC, SS, 9, 2);                        \
    REG_STAGE(CC, SS, 10, 1);                                                 \
    DPP_STAGE(CC, SS);                                                        \
} while (0)

#define MEASURE_REGBIT(q, m) do {                                             \
    float px_ = 0.f, py_ = 0.f, pz_ = 0.f;                                    \
    _Pragma("unroll")                                                         \
    for (int r_ = 0; r_ < 32; r_++) {                                         \
        const int j_ = r_ ^ (m);                                              \
        px_ += sv[r_].x * sv[j_].x + sv[r_].y * sv[j_].y;                     \
        const float imz_ = sv[r_].x * sv[j_].y - sv[r_].y * sv[j_].x;         \
        py_ += (r_ & (m)) ? -imz_ : imz_;                                     \
        const float p2_ = sv[r_].x * sv[r_].x + sv[r_].y * sv[r_].y;          \
        pz_ += (r_ & (m)) ? -p2_ : p2_;                                       \
    }                                                                         \
    px_ = wave_sum(px_); py_ = wave_sum(py_); pz_ = wave_sum(pz_);            \
    if (lane == 0) {                                                          \
        out[3 * (q) + 0] = px_;                                               \
        out[3 * (q) + 1] = py_;                                               \
        out[3 * (q) + 2] = pz_;                                               \
    }                                                                         \
} while (0)

#define MEASURE_Q5() do {                                                     \
    float px_ = 0.f, py_ = 0.f, pz_ = 0.f;                                    \
    const int bit_ = lane & 1;                                                \
    _Pragma("unroll")                                                         \
    for (int r_ = 0; r_ < 32; r_++) {                                         \
        const float pr_ = dpp_mov<0xB1>(sv[r_].x);                            \
        const float pi_ = dpp_mov<0xB1>(sv[r_].y);                            \
        px_ += sv[r_].x * pr_ + sv[r_].y * pi_;                               \
        const float imz_ = sv[r_].x * pi_ - sv[r_].y * pr_;                   \
        py_ += bit_ ? -imz_ : imz_;                                           \
        const float p2_ = sv[r_].x * sv[r_].x + sv[r_].y * sv[r_].y;          \
        pz_ += bit_ ? -p2_ : p2_;                                             \
    }                                                                         \
    px_ = wave_sum(px_); py_ = wave_sum(py_); pz_ = wave_sum(pz_);            \
    if (lane == 0) { out[15] = px_; out[16] = py_; out[17] = pz_; }           \
} while (0)

__global__ __launch_bounds__(256, 1) void quixer_kernel(
    const float* __restrict__ emb,    // [32,512]
    const float* __restrict__ Wang,   // [44,512]
    const float* __restrict__ bang,   // [44]
    const float* __restrict__ qc,     // [3]
    const float* __restrict__ lre,    // [32]
    const float* __restrict__ lim,    // [32]
    const float* __restrict__ ffp,    // [44]
    float* __restrict__ out)          // [33]
{
    __shared__ float2 ex[4][2048];    // 64 KB: exchange + per-wave transpose scratch

    const int tid  = threadIdx.x;
    const int w    = tid >> 6;        // wave id == token id
    const int lane = tid & 63;
    float2* ws = &ex[w][0];           // this wave's private 16 KB region

    // ---- small uniform inputs + ff sincos, early (load shadow) ----
    const float qc0 = qc[0], qc1 = qc[1], qc2 = qc[2];
    float relv = 0.f, imlv = 0.f;
    if (lane < 32) { relv = lre[lane]; imlv = lim[lane]; }

    float fC[NQ], fS[NQ], bsum[NQ];
#pragma unroll
    for (int q = 0; q < NQ; q++) {
        bsum[q] = bang[q] + bang[q + 22];
        const float fphi = ffp[q] + ffp[q + 22];
        __sincosf(0.5f * fphi, &fS[q], &fC[q]);
    }

    // ---- Phase A: 11 dots of 512, fused float4 loads + FMA, 2-deep pipe ----
    float C[NQ], S[NQ];
    {
        const float4* e4 = reinterpret_cast<const float4*>(emb + (w << 9));
        const float4 ev0 = e4[lane], ev1 = e4[lane + 64];

        const float4* w04 = reinterpret_cast<const float4*>(Wang);
        const float4* w14 = reinterpret_cast<const float4*>(Wang + (22 << 9));
        float4 a0 = w04[lane], a1 = w04[lane + 64];
        float4 b0 = w14[lane], b1 = w14[lane + 64];

        float part[NQ];
#pragma unroll
        for (int q = 0; q < NQ; q++) {
            float4 na0, na1, nb0, nb1;
            if (q < NQ - 1) {
                const float4* nw0 = reinterpret_cast<const float4*>(Wang + ((q + 1) << 9));
                const float4* nw1 = reinterpret_cast<const float4*>(Wang + ((q + 23) << 9));
                na0 = nw0[lane]; na1 = nw0[lane + 64];
                nb0 = nw1[lane]; nb1 = nw1[lane + 64];
            }
            part[q] = ev0.x * (a0.x + b0.x) + ev0.y * (a0.y + b0.y)
                    + ev0.z * (a0.z + b0.z) + ev0.w * (a0.w + b0.w)
                    + ev1.x * (a1.x + b1.x) + ev1.y * (a1.y + b1.y)
                    + ev1.z * (a1.z + b1.z) + ev1.w * (a1.w + b1.w);
            if (q < NQ - 1) { a0 = na0; a1 = na1; b0 = nb0; b1 = nb1; }
        }
#pragma unroll
        for (int q = 0; q < NQ; q++) {
            const float phi = wave_sum(part[q]) + bsum[q];
            __sincosf(0.5f * phi, &S[q], &C[q]);
        }
    }

    // ---- LCU coefficients ----
    float lrv[4], liv[4];
    {
        const float avn = sqrtf(relv * relv + imlv * imlv);
        const float denom = fmaxf(wave_sum(avn), 1e-8f);
#pragma unroll
        for (int t = 0; t < 4; t++) { lrv[t] = lre[t] / denom; liv[t] = lim[t] / denom; }
    }

    v2f sv[32], av[32];

    // ---- k=1: mono=e0, U_t|0> closed-form (REAL), half-width exchange ----
    // ||e0|| = 1 exactly, so the small-norm branch cannot fire (faithful skip).
    {
        float lp = 1.f;
#pragma unroll
        for (int q = 5; q < 11; q++)
            lp *= ((lane >> (10 - q)) & 1) ? S[q] : C[q];
        float t[32];
        t[0] = lp;
#pragma unroll
        for (int q = 4; q >= 0; q--) {
            const int m = 1 << (4 - q);
#pragma unroll
            for (int j = 0; j < 32; j++) {
                if (j < m) {
                    t[j | m] = t[j] * S[q];
                    t[j]     = t[j] * C[q];
                }
            }
        }
        float* wsf = (float*)ws;
#pragma unroll
        for (int r = 0; r < 32; r++) wsf[(r << 6) | lane] = t[r];
        __syncthreads();
        const float* exf = (const float*)(&ex[0][0]);
#pragma unroll
        for (int r = 0; r < 32; r++) {
            const int i = (r << 6) | lane;
            const float v0 = exf[i], v1 = exf[4096 + i];
            const float v2 = exf[8192 + i], v3 = exf[12288 + i];
            v2f m0;
            m0.x = lrv[0]*v0 + lrv[1]*v1 + lrv[2]*v2 + lrv[3]*v3;
            m0.y = liv[0]*v0 + liv[1]*v1 + liv[2]*v2 + liv[3]*v3;
            sv[r] = m0;
            av[r] = splat(qc1) * m0;         // acc = qc1*m1 (qc0*e0 added below)
        }
        if (lane == 0) av[0].x += qc0;
        __syncthreads();   // regions become transpose scratch next
    }

    // ---- k=2 small-norm check (faithful) on mono1 ----
    {
        float nsq = 0.f;
#pragma unroll
        for (int r = 0; r < 32; r++) nsq += sv[r].x * sv[r].x + sv[r].y * sv[r].y;
        nsq = wave_sum(nsq);
        if (sqrtf(nsq) < 1e-8f) {
#pragma unroll
            for (int r = 0; r < 32; r++) { sv[r].x = 0.f; sv[r].y = 0.f; }
            if (lane == 0) sv[0].x = 1.f;
        }
    }

    // ---- two-pass apply loop: ONE APPLY_CORE code instance ----
    // pass 0: token unitary (k=2) + LCU exchange + acc + normalize
    // pass 1: U_ff
    float uc[NQ], us[NQ];
#pragma unroll 1
    for (int p = 0; p < 2; p++) {
#pragma unroll
        for (int q = 0; q < NQ; q++) {
            uc[q] = p ? fC[q] : C[q];
            us[q] = p ? fS[q] : S[q];
        }
        APPLY_CORE(uc, us);   // A -> B

        if (p == 0) {
            T_B2A();          // back to A

            const float lr = lrv[w], li = liv[w];
#pragma unroll
            for (int r = 0; r < 32; r++) {
                const int i = (r << 6) | lane;
                ws[i] = make_float2(lr * sv[r].x - li * sv[r].y,
                                    lr * sv[r].y + li * sv[r].x);
            }
            __syncthreads();
#pragma unroll
            for (int r = 0; r < 32; r++) {
                const int i = (r << 6) | lane;
                const float2 v0 = ex[0][i], v1 = ex[1][i], v2 = ex[2][i], v3 = ex[3][i];
                v2f m0;
                m0.x = v0.x + v1.x + v2.x + v3.x;
                m0.y = v0.y + v1.y + v2.y + v3.y;
                av[r] += splat(qc2) * m0;
            }
            __syncthreads();   // regions reusable (pass-1 transpose scratch)

            // normalize acc (poly_norm cancels except in the 1e-8 check)
            const float pn = fmaxf(fabsf(qc0) + fabsf(qc1) + fabsf(qc2), 1e-8f);
            float snsq = 0.f;
#pragma unroll
            for (int r = 0; r < 32; r++) snsq += av[r].x * av[r].x + av[r].y * av[r].y;
            snsq = wave_sum(snsq);
            if (sqrtf(snsq) / pn < 1e-8f) {
#pragma unroll
                for (int r = 0; r < 32; r++) { sv[r].x = 0.f; sv[r].y = 0.f; }
                if (lane == 0) sv[0].x = 1.f;
            } else {
                const v2f inv = splat(1.f / sqrtf(snsq));
#pragma unroll
                for (int r = 0; r < 32; r++) sv[r] = av[r] * inv;
            }
        }
    }
    // sv now = U_ff * psi, layout B

    // ---- measurements: layout B (q5 DPP, q6..10 reg), then A (q0..4) ----
    switch (w) {
        case 0: MEASURE_REGBIT(8, 4);  break;
        case 1: MEASURE_Q5(); MEASURE_REGBIT(9, 2); break;
        case 2: MEASURE_REGBIT(6, 16); MEASURE_REGBIT(10, 1); break;
        case 3: MEASURE_REGBIT(7, 8);  break;
    }
    T_B2A();        // wave-private; no barrier needed
    switch (w) {
        case 0: MEASURE_REGBIT(0, 16); MEASURE_REGBIT(4, 1); break;
        case 1: MEASURE_REGBIT(1, 8);  break;
        case 2: MEASURE_REGBIT(2, 4);  break;
        case 3: MEASURE_REGBIT(3, 2);  break;
    }
}

extern "C" void kernel_launch(void* const* d_in, const int* in_sizes, int n_in,
                              void* d_out, int out_size, void* d_ws, size_t ws_size,
                              hipStream_t stream) {
    quixer_kernel<<<1, 256, 0, stream>>>(
        (const float*)d_in[0],  // tokens_emb [32,512]
        (const float*)d_in[1],  // W_angles   [44,512]
        (const float*)d_in[2],  // b_angles   [44]
        (const float*)d_in[3],  // qsvt_coeffs[3]
        (const float*)d_in[4],  // lcu_re     [32]
        (const float*)d_in[5],  // lcu_im     [32]
        (const float*)d_in[6],  // ff_params  [44]
        (float*)d_out);         // [33]
}